// Round 7
// baseline (2332.391 us; speedup 1.0000x reference)
//
#include <hip/hip_runtime.h>

typedef unsigned short u16;
typedef short bf16x8 __attribute__((ext_vector_type(8)));
typedef float f32x4 __attribute__((ext_vector_type(4)));

typedef const __attribute__((address_space(1))) void* gaddr_t;
typedef __attribute__((address_space(3))) void* laddr_t;

__device__ __forceinline__ u16 f2b(float f){
  unsigned u = __float_as_uint(f);
  u = (u + 0x7fffu + ((u >> 16) & 1u)) >> 16;
  return (u16)u;
}
__device__ __forceinline__ float b2f(u16 h){
  return __uint_as_float(((unsigned)h) << 16);
}
__device__ __forceinline__ float2 cmul(float2 a, float2 b){
  return make_float2(a.x*b.x - a.y*b.y, a.x*b.y + a.y*b.x);
}

// publisher-side coherent store: RELAXED agent atomic -> reaches device coherence point,
// no cache-maintenance ops, fire-and-forget (no latency chain).
__device__ __forceinline__ void cstore(float2* p, float2 x){
  unsigned long long v; __builtin_memcpy(&v, &x, 8);
  __hip_atomic_store((unsigned long long*)p, v, __ATOMIC_RELAXED, __HIP_MEMORY_SCOPE_AGENT);
}

// ---------------- merged cast + small builds ----------------
__global__ void cast_all(const float* __restrict__ x, const float* __restrict__ wa,
                         const float* __restrict__ wx, const float* __restrict__ wo,
                         const float* __restrict__ vr, const float* __restrict__ vi,
                         const float* __restrict__ lhr, const float* __restrict__ lhi,
                         u16* __restrict__ Xb, u16* __restrict__ WABb,
                         u16* __restrict__ WOb, u16* __restrict__ Mv,
                         u16* __restrict__ xroll){
  int i = blockIdx.x*blockDim.x + threadIdx.x;
  int st = gridDim.x*blockDim.x;
  for (int idx = i; idx < 4981760; idx += st){
    if (idx < 4849664){
      const float* s; u16* d; int o;
      if (idx < 4194304){ s = x; d = Xb; o = idx; }
      else if (idx < 4456448){ s = wa; d = WABb; o = idx - 4194304; }
      else if (idx < 4718592){ s = wx; d = WABb + 1048576; o = idx - 4456448; }
      else { s = wo; d = WOb; o = idx - 4718592; }
      float4 v = ((const float4*)s)[o];
      ushort4 r; r.x=f2b(v.x); r.y=f2b(v.y); r.z=f2b(v.z); r.w=f2b(v.w);
      ((ushort4*)d)[o] = r;
    } else if (idx < 4980736){
      int o = idx - 4849664;            // MV4: 512 rows x 256 ushort4
      int m = o >> 8, q = o & 255;
      float2 a = ((const float2*)vr)[m*256 + q];
      float2 b = ((const float2*)vi)[m*256 + q];
      ushort4 r; r.x=f2b(a.x); r.y=f2b(-b.x); r.z=f2b(a.y); r.w=f2b(-b.y);
      ((ushort4*)Mv)[o] = r;
    } else {
      int o = idx - 4980736;            // h0: 4 batches x 256 ushort4
      int b = o >> 8, c4 = o & 255;
      float4 v = (c4 < 128) ? ((const float4*)lhr)[c4] : ((const float4*)lhi)[c4-128];
      ushort4 r; r.x=f2b(v.x); r.y=f2b(v.y); r.z=f2b(v.z); r.w=f2b(v.w);
      ((ushort4*)xroll)[b*1048576 + c4] = r;
    }
  }
}

// ---------------- single-wave 32x32 complex GJ, full in-block pivoting ----------------
// T: LDS [32][66] float2; cols 0..31 = D, 32..63 = I -> becomes [I | D^-1]. lane 0..63.
__device__ __forceinline__ void gj32_wave(float2* T, int lane){
  const int LD = 66;
  #pragma unroll 1
  for (int k = 0; k < 32; ++k){
    float2 colv = make_float2(0.f, 0.f);
    float mag = -1.f;
    if (lane < 32){
      colv = T[lane*LD + k];
      if (lane >= k) mag = colv.x*colv.x + colv.y*colv.y;
    }
    int best = lane;
    #pragma unroll
    for (int off = 1; off < 64; off <<= 1){
      float om = __shfl_xor(mag, off);
      int ob  = __shfl_xor(best, off);
      if (om > mag || (om == mag && ob < best)){ mag = om; best = ob; }
    }
    const int p = best;                       // all lanes agree after full butterfly
    float pvx = __shfl(colv.x, p), pvy = __shfl(colv.y, p);
    float dinv = 1.f/(pvx*pvx + pvy*pvy);
    float2 pinv = make_float2(pvx*dinv, -pvy*dinv);
    float2 rk = T[k*LD + lane];
    float2 rp = T[p*LD + lane];
    float2 nk = cmul(rp, pinv);
    T[k*LD + lane] = nk;
    if (p != k) T[p*LD + lane] = rk;
    #pragma unroll 4
    for (int r = 0; r < 32; ++r){
      if (r == k) continue;
      float2 f = T[r*LD + k];
      float2 cell = T[r*LD + lane];
      cell.x -= f.x*nk.x - f.y*nk.y;
      cell.y -= f.x*nk.y + f.y*nk.x;
      T[r*LD + lane] = cell;
    }
  }
}

// ---------------- pipelined 32-block inversion ----------------
// flags: relaxed agent atomics. bulk publish: relaxed agent atomic stores.
// bulk consume: PLAIN wide loads — every ring slot is first-touch-once per replay,
// so no cache can hold a stale copy; miss is serviced from the coherence point.
__global__ __launch_bounds__(1024, 4) void inv_pipe(
    const float* __restrict__ vr, const float* __restrict__ vi,
    float2* __restrict__ PBUFg,   // [16][512][32]
    float2* __restrict__ BINVg,   // [16][32][32]
    int* __restrict__ FLAG,       // [16]
    u16* __restrict__ Mi)
{
  extern __shared__ char lds[];
  float2* Pb    = (float2*)lds;                       // [512][32] 128KB
  float2* Pv    = (float2*)(lds + 131072);            // [32][33]
  float2* BINVl = (float2*)(lds + 131072 + 8448);     // [32][33]
  float2* gjT   = (float2*)(lds + 131072);            // [32][66] overlays Pv+BINVl
  float2* T1l   = (float2*)(lds + 131072 + 16896);    // [32][33]

  const int tid = threadIdx.x, b = blockIdx.x;
  const int rg = tid >> 5, c = tid & 31;
  const bool left = b < 16;
  const int sj = left ? b : (b - 16);
  float2 reg[16];

  if (left){
    #pragma unroll
    for (int t = 0; t < 16; ++t){
      int r = t*32 + rg;
      reg[t] = make_float2(vr[r*512 + b*32 + c], vi[r*512 + b*32 + c]);
    }
  } else {
    #pragma unroll
    for (int t = 0; t < 16; ++t){
      int r = t*32 + rg;
      reg[t] = make_float2((r == sj*32 + c) ? 1.f : 0.f, 0.f);
    }
  }

  auto publish = [&](int e){
    float2* dst = PBUFg + (size_t)e*16384;
    #pragma unroll
    for (int t = 0; t < 16; ++t)
      cstore(&dst[(t*32+rg)*32 + c], reg[t]);
  };

  if (b == 0){                                  // E_0: raw strip + inv(V[0:32,0:32])
    publish(0);
    gjT[rg*66 + c]      = reg[0];
    gjT[rg*66 + 32 + c] = make_float2((rg==c)?1.f:0.f, 0.f);
    __syncthreads();
    if (tid < 64) gj32_wave(gjT, tid);
    __syncthreads();
    cstore(&BINVg[rg*32 + c], gjT[rg*66 + 32 + c]);
    asm volatile("s_waitcnt vmcnt(0)" ::: "memory");
    __syncthreads();
    if (tid == 0) __hip_atomic_store(&FLAG[0], 1, __ATOMIC_RELAXED, __HIP_MEMORY_SCOPE_AGENT);
    return;
  }

  const int k0 = left ? 0 : sj;     // right strip sj is pristine (zero pivot rows) before step sj
  const int lastk = left ? b : 16;
  #pragma unroll 1
  for (int k = k0; k < lastk; ++k){
    const bool owner = left && (k == b-1);
    if (tid == 0){
      while (__hip_atomic_load(&FLAG[k], __ATOMIC_RELAXED, __HIP_MEMORY_SCOPE_AGENT) == 0)
        __builtin_amdgcn_s_sleep(1);
    }
    __syncthreads();
    // stage PBUF_k, BINV_k with PLAIN coalesced loads (first-touch); own pivot rows -> Pv
    {
      const float2* src = PBUFg + (size_t)k*16384;
      #pragma unroll
      for (int t = 0; t < 16; ++t)
        Pb[(t*32+rg)*32 + c] = src[(t*32+rg)*32 + c];
      BINVl[rg*33 + c] = BINVg[(size_t)k*1024 + rg*32 + c];
      #pragma unroll
      for (int t = 0; t < 16; ++t) if (t == k) Pv[rg*33 + c] = reg[t];
    }
    __syncthreads();
    // T1 = BINV * pivrows ; new pivot rows
    {
      float2 acc = make_float2(0.f, 0.f);
      #pragma unroll
      for (int kk = 0; kk < 32; ++kk){
        float2 bv = BINVl[rg*33 + kk], sv = Pv[kk*33 + c];
        acc.x += bv.x*sv.x - bv.y*sv.y;
        acc.y += bv.x*sv.y + bv.y*sv.x;
      }
      T1l[rg*33 + c] = acc;
      #pragma unroll
      for (int t = 0; t < 16; ++t) if (t == k) reg[t] = acc;
    }
    __syncthreads();            // T1l ready; Pv/BINVl dead (gjT may overlay)

    if (owner){
      // update next diag rows (t == k+1 == b) first, seed gjT
      #pragma unroll
      for (int t = 0; t < 16; ++t) if (t == k+1){
        float2 v = reg[t];
        #pragma unroll
        for (int kk = 0; kk < 32; ++kk){
          float2 f = Pb[(t*32+rg)*32 + kk], s = T1l[kk*33 + c];
          v.x -= f.x*s.x - f.y*s.y;
          v.y -= f.x*s.y + f.y*s.x;
        }
        reg[t] = v;
        gjT[rg*66 + c]      = v;
        gjT[rg*66 + 32 + c] = make_float2((rg==c)?1.f:0.f, 0.f);
      }
      __syncthreads();          // Dg ready
      if (tid < 64) gj32_wave(gjT, tid);   // wave 0: GJ; others fall through to update
      #pragma unroll
      for (int h = 0; h < 2; ++h){
        float2 t1c[16];
        #pragma unroll
        for (int kk = 0; kk < 16; ++kk) t1c[kk] = T1l[(h*16+kk)*33 + c];
        #pragma unroll
        for (int t = 0; t < 16; ++t){
          if (t == k || t == k+1) continue;
          float2 v = reg[t];
          #pragma unroll
          for (int kk = 0; kk < 16; ++kk){
            float2 f = Pb[(t*32+rg)*32 + h*16 + kk];
            v.x -= f.x*t1c[kk].x - f.y*t1c[kk].y;
            v.y -= f.x*t1c[kk].y + f.y*t1c[kk].x;
          }
          reg[t] = v;
        }
      }
      __syncthreads();          // GJ + updates done
      publish(k+1);
      cstore(&BINVg[(size_t)(k+1)*1024 + rg*32 + c], gjT[rg*66 + 32 + c]);
      asm volatile("s_waitcnt vmcnt(0)" ::: "memory");
      __syncthreads();
      if (tid == 0) __hip_atomic_store(&FLAG[k+1], 1, __ATOMIC_RELAXED, __HIP_MEMORY_SCOPE_AGENT);
    } else {
      #pragma unroll
      for (int h = 0; h < 2; ++h){
        float2 t1c[16];
        #pragma unroll
        for (int kk = 0; kk < 16; ++kk) t1c[kk] = T1l[(h*16+kk)*33 + c];
        #pragma unroll
        for (int t = 0; t < 16; ++t){
          if (t == k) continue;
          float2 v = reg[t];
          #pragma unroll
          for (int kk = 0; kk < 16; ++kk){
            float2 f = Pb[(t*32+rg)*32 + h*16 + kk];
            v.x -= f.x*t1c[kk].x - f.y*t1c[kk].y;
            v.y -= f.x*t1c[kk].y + f.y*t1c[kk].x;
          }
          reg[t] = v;
        }
      }
      __syncthreads();          // before next stage overwrites Pb
    }
  }

  if (!left){                   // MINV: real embedding of V^-1, bf16
    #pragma unroll
    for (int t = 0; t < 16; ++t){
      int m = t*32 + rg;
      int kcol = sj*32 + c;
      float xr = reg[t].x, xi = reg[t].y;
      Mi[(size_t)(2*m)*1024 + kcol]         = f2b(xr);
      Mi[(size_t)(2*m)*1024 + 512 + kcol]   = f2b(-xi);
      Mi[(size_t)(2*m+1)*1024 + kcol]       = f2b(xi);
      Mi[(size_t)(2*m+1)*1024 + 512 + kcol] = f2b(xr);
    }
  }
}

// ---------------- GEMM: 256x256 tile, 8-wave, BK=32, 4-deep LDS ring ----------------
enum { EPI_BF16 = 0, EPI_ADDXC = 3, EPI_OUTF32 = 4, EPI_AX = 5 };

#define MFMA_BF16(a,b,c) __builtin_amdgcn_mfma_f32_16x16x32_bf16(a,b,c,0,0,0)

template<int EPI>
__global__ __launch_bounds__(512, 2) void gemm256(
    const u16* __restrict__ A, const u16* __restrict__ B,
    int K, int NT, int N, int byShift,
    void* __restrict__ C, void* __restrict__ aux0, void* __restrict__ aux1,
    void* __restrict__ aux2)
{
  extern __shared__ u16 LDS[];   // 65536 u16 = 128 KB
  const int tid = threadIdx.x;
  const int w = tid >> 6, lane = tid & 63;
  const int wm = w >> 2, wn = w & 3;
  const int fr = lane & 15, kg = lane >> 4;

  const int cpx = gridDim.x >> 3;
  const int bid = blockIdx.x;
  const int swz = (bid & 7)*cpx + (bid >> 3);
  const int by = swz & ((1 << byShift) - 1), bx = swz >> byShift;
  const size_t arow0 = (size_t)bx * 256;
  const int bcol0 = by * 256;

  const int rL = w*16 + (lane >> 2);
  const int glog = (lane & 3) ^ ((lane >> 3) & 3);
  const u16* Asrc = A + (arow0 + rL)*(size_t)K + glog*8;
  const u16* Bsrc = B + ((size_t)(bcol0 + rL))*K + glog*8;
  const size_t KH = (size_t)128 * K;
  const int sdst = w*512;

  const int goff = (kg ^ ((fr >> 1) & 3)) * 8;
  const int aro = wm*4096 + fr*32 + goff;
  const int bro = 32768 + (wn>>1)*4096 + (wn&1)*2048 + fr*32 + goff;

  f32x4 acc[8][4] = {};
  bf16x8 bfr[4];

  auto STG_A = [&](int kt){
    int bo = (kt & 3)*8192;
    #pragma unroll
    for (int h = 0; h < 2; ++h)
      __builtin_amdgcn_global_load_lds((gaddr_t)(Asrc + h*KH + kt*32),
          (laddr_t)(LDS + bo + h*4096 + sdst), 16, 0, 0);
  };
  auto STG_B = [&](int kt){
    int bo = 32768 + (kt & 3)*8192;
    #pragma unroll
    for (int h = 0; h < 2; ++h)
      __builtin_amdgcn_global_load_lds((gaddr_t)(Bsrc + h*KH + kt*32),
          (laddr_t)(LDS + bo + h*4096 + sdst), 16, 0, 0);
  };

  auto TILE = [&](int kt, int stg, int wait){
    const int ab = (kt & 3)*8192 + aro;
    const int bb = (kt & 3)*8192 + bro;
    bf16x8 af[4];
    #pragma unroll
    for (int m = 0; m < 4; ++m) af[m] = *(const bf16x8*)&LDS[ab + m*512];
    #pragma unroll
    for (int n = 0; n < 4; ++n) bfr[n] = *(const bf16x8*)&LDS[bb + n*512];
    if (stg) STG_A(kt + 3);
    __builtin_amdgcn_s_barrier();
    __builtin_amdgcn_s_setprio(1);
    #pragma unroll
    for (int m = 0; m < 4; ++m)
      #pragma unroll
      for (int n = 0; n < 4; ++n)
        acc[m][n] = MFMA_BF16(af[m], bfr[n], acc[m][n]);
    __builtin_amdgcn_s_setprio(0);
    __builtin_amdgcn_s_barrier();
    #pragma unroll
    for (int m = 0; m < 4; ++m) af[m] = *(const bf16x8*)&LDS[ab + (m+4)*512];
    if (stg) STG_B(kt + 3);
    __builtin_amdgcn_s_barrier();
    __builtin_amdgcn_s_setprio(1);
    #pragma unroll
    for (int m = 0; m < 4; ++m)
      #pragma unroll
      for (int n = 0; n < 4; ++n)
        acc[m+4][n] = MFMA_BF16(af[m], bfr[n], acc[m+4][n]);
    __builtin_amdgcn_s_setprio(0);
    if (wait == 2){ asm volatile("s_waitcnt vmcnt(8)" ::: "memory"); }
    else if (wait == 1){ asm volatile("s_waitcnt vmcnt(4)" ::: "memory"); }
    else if (wait == 0){ asm volatile("s_waitcnt vmcnt(0)" ::: "memory"); }
    __builtin_amdgcn_sched_barrier(0);
    __builtin_amdgcn_s_barrier();
  };

  STG_A(0); STG_B(0); STG_A(1); STG_B(1); STG_A(2); STG_B(2);
  asm volatile("s_waitcnt vmcnt(8)" ::: "memory");
  __builtin_amdgcn_sched_barrier(0);
  __builtin_amdgcn_s_barrier();

  #pragma unroll 1
  for (int kt = 0; kt < NT - 3; ++kt) TILE(kt, 1, 2);
  TILE(NT-3, 0, 1);
  TILE(NT-2, 0, 0);
  TILE(NT-1, 0, -1);

  const int rbase = wm*128 + (lane >> 4)*4;
  const int cbase = wn*64 + fr;
  #pragma unroll
  for (int M = 0; M < 8; ++M){
    #pragma unroll
    for (int Np = 0; Np < 4; ++Np){
      #pragma unroll
      for (int j = 0; j < 4; ++j){
        float v = acc[M][Np][j];
        size_t gr = arow0 + rbase + M*16 + j;
        int gc = bcol0 + cbase + Np*16;
        if constexpr (EPI == EPI_BF16){
          ((u16*)C)[gr*(size_t)N + gc] = f2b(v);
        } else if constexpr (EPI == EPI_OUTF32){
          ((float*)C)[gr*(size_t)N + gc] = v;
        } else if constexpr (EPI == EPI_ADDXC){
          float xc = b2f(((const u16*)aux0)[gr*512 + gc]);
          ((u16*)C)[gr*512 + gc] = f2b(v + xc);
        } else { // EPI_AX
          float pv = __shfl_xor(v, 1);
          int odd = lane & 1;
          float re = odd ? pv : v;
          float im = odd ? v : pv;
          float m2 = re*re + im*im;
          if (gc < 1024){
            int mh = gc >> 1;
            float sc = m2 > 0.f ? sqrtf(m2)/(1.f + m2) : 0.f;  // sigmoid(log m) = m/(1+m)
            if (!odd){
              unsigned pk = (unsigned)f2b(re*sc) | ((unsigned)f2b(im*sc) << 16);
              ((unsigned*)aux0)[gr*512 + mh] = pk;             // interleaved complex a
            }
          } else {
            int mh = (gc - 1024) >> 1;
            float sc = sqrtf(m2);                              // xc = x2 * sqrt(m)
            u16 ob = f2b(v * sc);
            if (!odd) ((u16*)aux1)[gr*512 + mh] = ob;          // xc_re
            int t = (int)(gr & 4095);
            if (t != 4095)                                     // x_roll[t+1] = xc[t]
              ((u16*)aux2)[(gr+1)*1024 + (odd ? 512 + mh : mh)] = ob;
          }
        }
      }
    }
  }
}

// ---------------- scan: s_t = a_t*(s_{t-1}+u_t), chunked 3-phase ----------------
__global__ void scan_p1(const unsigned* __restrict__ aint, const unsigned* __restrict__ uint_,
                        float4* __restrict__ agg){
  int idx = blockIdx.x*256 + threadIdx.x;   // 4*64*512 = 131072
  int m = idx & 511, chunk = (idx >> 9) & 63, b = idx >> 15;
  size_t row = (size_t)b*4096 + chunk*64;
  float px=1.f, py=0.f, sx=0.f, sy=0.f;
  for (int i = 0; i < 64; ++i, ++row){
    unsigned av = aint[row*512 + m];
    unsigned uv = uint_[row*512 + m];
    float ar = b2f((u16)av), ai = b2f((u16)(av>>16));
    float ur = b2f((u16)uv), ui = b2f((u16)(uv>>16));
    float tx2 = sx + ur, ty2 = sy + ui;
    sx = ar*tx2 - ai*ty2; sy = ar*ty2 + ai*tx2;
    float np = px*ar - py*ai; py = px*ai + py*ar; px = np;
  }
  agg[((size_t)(b*512+m))*64 + chunk] = make_float4(px,py,sx,sy);
}
__global__ void scan_p2(const float4* __restrict__ agg, float2* __restrict__ carry){
  int seq = blockIdx.x*256 + threadIdx.x;   // 2048
  float sx = 0.f, sy = 0.f;
  for (int c = 0; c < 64; ++c){
    carry[(size_t)seq*64 + c] = make_float2(sx, sy);
    float4 g = agg[(size_t)seq*64 + c];
    float nx = g.x*sx - g.y*sy + g.z;
    sy = g.x*sy + g.y*sx + g.w; sx = nx;
  }
}
__global__ void scan_p3(const unsigned* __restrict__ aint, const unsigned* __restrict__ uint_,
                        const float2* __restrict__ carry, unsigned* __restrict__ sout){
  int idx = blockIdx.x*256 + threadIdx.x;
  int m = idx & 511, chunk = (idx >> 9) & 63, b = idx >> 15;
  size_t row = (size_t)b*4096 + chunk*64;
  float2 c0 = carry[((size_t)(b*512+m))*64 + chunk];
  float sx = c0.x, sy = c0.y;
  for (int i = 0; i < 64; ++i, ++row){
    unsigned av = aint[row*512 + m];
    unsigned uv = uint_[row*512 + m];
    float ar = b2f((u16)av), ai = b2f((u16)(av>>16));
    float ur = b2f((u16)uv), ui = b2f((u16)(uv>>16));
    float tx2 = sx + ur, ty2 = sy + ui;
    sx = ar*tx2 - ai*ty2; sy = ar*ty2 + ai*tx2;
    sout[row*512 + m] = (unsigned)f2b(sx) | ((unsigned)f2b(sy) << 16);
  }
}

// ---------------- host ----------------
extern "C" void kernel_launch(void* const* d_in, const int* in_sizes, int n_in,
                              void* d_out, int out_size, void* d_ws, size_t ws_size,
                              hipStream_t stream){
  (void)in_sizes; (void)n_in; (void)out_size; (void)ws_size;
  const float* x   = (const float*)d_in[0];
  const float* wa  = (const float*)d_in[1];
  const float* wx  = (const float*)d_in[2];
  const float* wo  = (const float*)d_in[3];
  const float* vr  = (const float*)d_in[4];
  const float* vi  = (const float*)d_in[5];
  const float* lhr = (const float*)d_in[6];
  const float* lhi = (const float*)d_in[7];

  char* ws = (char*)d_ws;
  const size_t SB = 16384ull*1024*2;      // 33.5 MB
  const size_t HB = SB/2;
  u16* Xb    = (u16*)(ws);                // later reused as U
  unsigned* AINT = (unsigned*)(ws + SB);  // interleaved a ; later HRE
  u16* XROLL = (u16*)(ws + 2*SB);         // later reused as S
  u16* XCRE  = (u16*)(ws + 3*SB);
  char* p = ws + 3*SB + HB;
  u16* WABb  = (u16*)p; p += 4194304;     // [WA;WX] 2048x1024 bf16
  u16* MINV  = (u16*)p; p += 2097152;
  u16* MV4   = (u16*)p; p += 1048576;
  u16* WOUTb = (u16*)p; p += 1048576;
  float2* PBUFg = (float2*)p; p += 16ull*16384*8;   // 2 MB
  float2* BINVg = (float2*)p; p += 16ull*1024*8;    // 128 KB
  int*    FLAG  = (int*)p;   p += 256;
  float4* AGG   = (float4*)p; p += 2048ull*64*16;
  float2* CARRY = (float2*)p; p += 2048ull*64*8;
  u16* U   = Xb;
  u16* S   = XROLL;
  u16* HRE = (u16*)AINT;

  hipMemsetAsync(FLAG, 0, 256, stream);

  cast_all<<<2048,256,0,stream>>>(x, wa, wx, wo, vr, vi, lhr, lhi,
                                  Xb, WABb, WOUTb, MV4, XROLL);

  const size_t ILDS = 131072 + 16896 + 8448;   // 156416
  inv_pipe<<<32,1024,ILDS,stream>>>(vr, vi, PBUFg, BINVg, FLAG, MINV);

  const size_t GLDS = 131072;
  gemm256<EPI_AX><<<512,512,GLDS,stream>>>(Xb, WABb, 1024, 32, 2048, 3,
                                           nullptr, (void*)AINT, (void*)XCRE, (void*)XROLL);
  gemm256<EPI_BF16><<<256,512,GLDS,stream>>>(XROLL, MINV, 1024, 32, 1024, 2,
                                             (void*)U, nullptr, nullptr, nullptr);

  scan_p1<<<512,256,0,stream>>>((const unsigned*)AINT, (const unsigned*)U, AGG);
  scan_p2<<<8,256,0,stream>>>(AGG, CARRY);
  scan_p3<<<512,256,0,stream>>>((const unsigned*)AINT, (const unsigned*)U, CARRY, (unsigned*)S);

  gemm256<EPI_ADDXC><<<128,512,GLDS,stream>>>(S, MV4, 1024, 32, 512, 1,
                                              (void*)HRE, (void*)XCRE, nullptr, nullptr);
  gemm256<EPI_OUTF32><<<256,512,GLDS,stream>>>(HRE, WOUTb, 512, 16, 1024, 2,
                                               d_out, nullptr, nullptr, nullptr);
}

// Round 8
// 2292.645 us; speedup vs baseline: 1.0173x; 1.0173x over previous
//
#include <hip/hip_runtime.h>

typedef unsigned short u16;
typedef short bf16x8 __attribute__((ext_vector_type(8)));
typedef float f32x4 __attribute__((ext_vector_type(4)));

typedef const __attribute__((address_space(1))) void* gaddr_t;
typedef __attribute__((address_space(3))) void* laddr_t;

__device__ __forceinline__ u16 f2b(float f){
  unsigned u = __float_as_uint(f);
  u = (u + 0x7fffu + ((u >> 16) & 1u)) >> 16;
  return (u16)u;
}
__device__ __forceinline__ float b2f(u16 h){
  return __uint_as_float(((unsigned)h) << 16);
}
__device__ __forceinline__ float2 cmul(float2 a, float2 b){
  return make_float2(a.x*b.x - a.y*b.y, a.x*b.y + a.y*b.x);
}

// publisher-side coherent store: RELAXED agent atomic -> reaches device coherence point,
// no cache-maintenance ops, fire-and-forget (no latency chain).
__device__ __forceinline__ void cstore(float2* p, float2 x){
  unsigned long long v; __builtin_memcpy(&v, &x, 8);
  __hip_atomic_store((unsigned long long*)p, v, __ATOMIC_RELAXED, __HIP_MEMORY_SCOPE_AGENT);
}
// flag ops MUST be RMWs: RMW is routed to the coherence point (cannot be served by a
// stale clean line in the local non-coherent XCD L2, unlike a relaxed atomic LOAD).
__device__ __forceinline__ int flag_read(int* p){
  return __hip_atomic_fetch_add(p, 0, __ATOMIC_RELAXED, __HIP_MEMORY_SCOPE_AGENT);
}
__device__ __forceinline__ void flag_set(int* p){
  __hip_atomic_fetch_add(p, 1, __ATOMIC_RELAXED, __HIP_MEMORY_SCOPE_AGENT);
}

// ---------------- merged cast + small builds ----------------
__global__ void cast_all(const float* __restrict__ x, const float* __restrict__ wa,
                         const float* __restrict__ wx, const float* __restrict__ wo,
                         const float* __restrict__ vr, const float* __restrict__ vi,
                         const float* __restrict__ lhr, const float* __restrict__ lhi,
                         u16* __restrict__ Xb, u16* __restrict__ WABb,
                         u16* __restrict__ WOb, u16* __restrict__ Mv,
                         u16* __restrict__ xroll){
  int i = blockIdx.x*blockDim.x + threadIdx.x;
  int st = gridDim.x*blockDim.x;
  for (int idx = i; idx < 4981760; idx += st){
    if (idx < 4849664){
      const float* s; u16* d; int o;
      if (idx < 4194304){ s = x; d = Xb; o = idx; }
      else if (idx < 4456448){ s = wa; d = WABb; o = idx - 4194304; }
      else if (idx < 4718592){ s = wx; d = WABb + 1048576; o = idx - 4456448; }
      else { s = wo; d = WOb; o = idx - 4718592; }
      float4 v = ((const float4*)s)[o];
      ushort4 r; r.x=f2b(v.x); r.y=f2b(v.y); r.z=f2b(v.z); r.w=f2b(v.w);
      ((ushort4*)d)[o] = r;
    } else if (idx < 4980736){
      int o = idx - 4849664;            // MV4: 512 rows x 256 ushort4
      int m = o >> 8, q = o & 255;
      float2 a = ((const float2*)vr)[m*256 + q];
      float2 b = ((const float2*)vi)[m*256 + q];
      ushort4 r; r.x=f2b(a.x); r.y=f2b(-b.x); r.z=f2b(a.y); r.w=f2b(-b.y);
      ((ushort4*)Mv)[o] = r;
    } else {
      int o = idx - 4980736;            // h0: 4 batches x 256 ushort4
      int b = o >> 8, c4 = o & 255;
      float4 v = (c4 < 128) ? ((const float4*)lhr)[c4] : ((const float4*)lhi)[c4-128];
      ushort4 r; r.x=f2b(v.x); r.y=f2b(v.y); r.z=f2b(v.z); r.w=f2b(v.w);
      ((ushort4*)xroll)[b*1048576 + c4] = r;
    }
  }
}

// ---------------- single-wave 32x32 complex GJ, full in-block pivoting ----------------
// T: LDS [32][66] float2; cols 0..31 = D, 32..63 = I -> becomes [I | D^-1]. lane 0..63.
__device__ __forceinline__ void gj32_wave(float2* T, int lane){
  const int LD = 66;
  #pragma unroll 1
  for (int k = 0; k < 32; ++k){
    float2 colv = make_float2(0.f, 0.f);
    float mag = -1.f;
    if (lane < 32){
      colv = T[lane*LD + k];
      if (lane >= k) mag = colv.x*colv.x + colv.y*colv.y;
    }
    int best = lane;
    #pragma unroll
    for (int off = 1; off < 64; off <<= 1){
      float om = __shfl_xor(mag, off);
      int ob  = __shfl_xor(best, off);
      if (om > mag || (om == mag && ob < best)){ mag = om; best = ob; }
    }
    const int p = best;                       // all lanes agree after full butterfly
    float pvx = __shfl(colv.x, p), pvy = __shfl(colv.y, p);
    float dinv = 1.f/(pvx*pvx + pvy*pvy);
    float2 pinv = make_float2(pvx*dinv, -pvy*dinv);
    float2 rk = T[k*LD + lane];
    float2 rp = T[p*LD + lane];
    float2 nk = cmul(rp, pinv);
    T[k*LD + lane] = nk;
    if (p != k) T[p*LD + lane] = rk;
    #pragma unroll 4
    for (int r = 0; r < 32; ++r){
      if (r == k) continue;
      float2 f = T[r*LD + k];
      float2 cell = T[r*LD + lane];
      cell.x -= f.x*nk.x - f.y*nk.y;
      cell.y -= f.x*nk.y + f.y*nk.x;
      T[r*LD + lane] = cell;
    }
  }
}

// ---------------- pipelined 32-block inversion ----------------
// flags: relaxed agent atomic RMWs (coherence-point routed). bulk publish: relaxed
// agent atomic stores. bulk consume: PLAIN wide loads (first-touch-once per replay).
__global__ __launch_bounds__(1024, 4) void inv_pipe(
    const float* __restrict__ vr, const float* __restrict__ vi,
    float2* __restrict__ PBUFg,   // [16][512][32]
    float2* __restrict__ BINVg,   // [16][32][32]
    int* __restrict__ FLAG,       // [16]
    u16* __restrict__ Mi)
{
  extern __shared__ char lds[];
  float2* Pb    = (float2*)lds;                       // [512][32] 128KB
  float2* Pv    = (float2*)(lds + 131072);            // [32][33]
  float2* BINVl = (float2*)(lds + 131072 + 8448);     // [32][33]
  float2* gjT   = (float2*)(lds + 131072);            // [32][66] overlays Pv+BINVl
  float2* T1l   = (float2*)(lds + 131072 + 16896);    // [32][33]

  const int tid = threadIdx.x, b = blockIdx.x;
  const int rg = tid >> 5, c = tid & 31;
  const bool left = b < 16;
  const int sj = left ? b : (b - 16);
  float2 reg[16];

  if (left){
    #pragma unroll
    for (int t = 0; t < 16; ++t){
      int r = t*32 + rg;
      reg[t] = make_float2(vr[r*512 + b*32 + c], vi[r*512 + b*32 + c]);
    }
  } else {
    #pragma unroll
    for (int t = 0; t < 16; ++t){
      int r = t*32 + rg;
      reg[t] = make_float2((r == sj*32 + c) ? 1.f : 0.f, 0.f);
    }
  }

  auto publish = [&](int e){
    float2* dst = PBUFg + (size_t)e*16384;
    #pragma unroll
    for (int t = 0; t < 16; ++t)
      cstore(&dst[(t*32+rg)*32 + c], reg[t]);
  };

  if (b == 0){                                  // E_0: raw strip + inv(V[0:32,0:32])
    publish(0);
    gjT[rg*66 + c]      = reg[0];
    gjT[rg*66 + 32 + c] = make_float2((rg==c)?1.f:0.f, 0.f);
    __syncthreads();
    if (tid < 64) gj32_wave(gjT, tid);
    __syncthreads();
    cstore(&BINVg[rg*32 + c], gjT[rg*66 + 32 + c]);
    asm volatile("s_waitcnt vmcnt(0)" ::: "memory");
    __syncthreads();
    if (tid == 0) flag_set(&FLAG[0]);
    return;
  }

  const int k0 = left ? 0 : sj;     // right strip sj is pristine (zero pivot rows) before step sj
  const int lastk = left ? b : 16;
  #pragma unroll 1
  for (int k = k0; k < lastk; ++k){
    const bool owner = left && (k == b-1);
    if (tid == 0){
      while (flag_read(&FLAG[k]) == 0)
        __builtin_amdgcn_s_sleep(1);
    }
    __syncthreads();
    // stage PBUF_k, BINV_k with PLAIN coalesced loads (first-touch); own pivot rows -> Pv
    {
      const float2* src = PBUFg + (size_t)k*16384;
      #pragma unroll
      for (int t = 0; t < 16; ++t)
        Pb[(t*32+rg)*32 + c] = src[(t*32+rg)*32 + c];
      BINVl[rg*33 + c] = BINVg[(size_t)k*1024 + rg*32 + c];
      #pragma unroll
      for (int t = 0; t < 16; ++t) if (t == k) Pv[rg*33 + c] = reg[t];
    }
    __syncthreads();
    // T1 = BINV * pivrows ; new pivot rows
    {
      float2 acc = make_float2(0.f, 0.f);
      #pragma unroll
      for (int kk = 0; kk < 32; ++kk){
        float2 bv = BINVl[rg*33 + kk], sv = Pv[kk*33 + c];
        acc.x += bv.x*sv.x - bv.y*sv.y;
        acc.y += bv.x*sv.y + bv.y*sv.x;
      }
      T1l[rg*33 + c] = acc;
      #pragma unroll
      for (int t = 0; t < 16; ++t) if (t == k) reg[t] = acc;
    }
    __syncthreads();            // T1l ready; Pv/BINVl dead (gjT may overlay)

    if (owner){
      // update next diag rows (t == k+1 == b) first, seed gjT
      #pragma unroll
      for (int t = 0; t < 16; ++t) if (t == k+1){
        float2 v = reg[t];
        #pragma unroll
        for (int kk = 0; kk < 32; ++kk){
          float2 f = Pb[(t*32+rg)*32 + kk], s = T1l[kk*33 + c];
          v.x -= f.x*s.x - f.y*s.y;
          v.y -= f.x*s.y + f.y*s.x;
        }
        reg[t] = v;
        gjT[rg*66 + c]      = v;
        gjT[rg*66 + 32 + c] = make_float2((rg==c)?1.f:0.f, 0.f);
      }
      __syncthreads();          // Dg ready
      if (tid < 64) gj32_wave(gjT, tid);   // wave 0: GJ; others fall through to update
      #pragma unroll
      for (int h = 0; h < 2; ++h){
        float2 t1c[16];
        #pragma unroll
        for (int kk = 0; kk < 16; ++kk) t1c[kk] = T1l[(h*16+kk)*33 + c];
        #pragma unroll
        for (int t = 0; t < 16; ++t){
          if (t == k || t == k+1) continue;
          float2 v = reg[t];
          #pragma unroll
          for (int kk = 0; kk < 16; ++kk){
            float2 f = Pb[(t*32+rg)*32 + h*16 + kk];
            v.x -= f.x*t1c[kk].x - f.y*t1c[kk].y;
            v.y -= f.x*t1c[kk].y + f.y*t1c[kk].x;
          }
          reg[t] = v;
        }
      }
      __syncthreads();          // GJ + updates done
      publish(k+1);
      cstore(&BINVg[(size_t)(k+1)*1024 + rg*32 + c], gjT[rg*66 + 32 + c]);
      asm volatile("s_waitcnt vmcnt(0)" ::: "memory");
      __syncthreads();
      if (tid == 0) flag_set(&FLAG[k+1]);
    } else {
      #pragma unroll
      for (int h = 0; h < 2; ++h){
        float2 t1c[16];
        #pragma unroll
        for (int kk = 0; kk < 16; ++kk) t1c[kk] = T1l[(h*16+kk)*33 + c];
        #pragma unroll
        for (int t = 0; t < 16; ++t){
          if (t == k) continue;
          float2 v = reg[t];
          #pragma unroll
          for (int kk = 0; kk < 16; ++kk){
            float2 f = Pb[(t*32+rg)*32 + h*16 + kk];
            v.x -= f.x*t1c[kk].x - f.y*t1c[kk].y;
            v.y -= f.x*t1c[kk].y + f.y*t1c[kk].x;
          }
          reg[t] = v;
        }
      }
      __syncthreads();          // before next stage overwrites Pb
    }
  }

  if (!left){                   // MINV: real embedding of V^-1, bf16
    #pragma unroll
    for (int t = 0; t < 16; ++t){
      int m = t*32 + rg;
      int kcol = sj*32 + c;
      float xr = reg[t].x, xi = reg[t].y;
      Mi[(size_t)(2*m)*1024 + kcol]         = f2b(xr);
      Mi[(size_t)(2*m)*1024 + 512 + kcol]   = f2b(-xi);
      Mi[(size_t)(2*m+1)*1024 + kcol]       = f2b(xi);
      Mi[(size_t)(2*m+1)*1024 + 512 + kcol] = f2b(xr);
    }
  }
}

// ---------------- GEMM: 256x256 tile, 8-wave, BK=32, 4-deep LDS ring ----------------
enum { EPI_BF16 = 0, EPI_ADDXC = 3, EPI_OUTF32 = 4, EPI_AX = 5 };

#define MFMA_BF16(a,b,c) __builtin_amdgcn_mfma_f32_16x16x32_bf16(a,b,c,0,0,0)

template<int EPI>
__global__ __launch_bounds__(512, 2) void gemm256(
    const u16* __restrict__ A, const u16* __restrict__ B,
    int K, int NT, int N, int byShift,
    void* __restrict__ C, void* __restrict__ aux0, void* __restrict__ aux1,
    void* __restrict__ aux2)
{
  extern __shared__ u16 LDS[];   // 65536 u16 = 128 KB
  const int tid = threadIdx.x;
  const int w = tid >> 6, lane = tid & 63;
  const int wm = w >> 2, wn = w & 3;
  const int fr = lane & 15, kg = lane >> 4;

  const int cpx = gridDim.x >> 3;
  const int bid = blockIdx.x;
  const int swz = (bid & 7)*cpx + (bid >> 3);
  const int by = swz & ((1 << byShift) - 1), bx = swz >> byShift;
  const size_t arow0 = (size_t)bx * 256;
  const int bcol0 = by * 256;

  const int rL = w*16 + (lane >> 2);
  const int glog = (lane & 3) ^ ((lane >> 3) & 3);
  const u16* Asrc = A + (arow0 + rL)*(size_t)K + glog*8;
  const u16* Bsrc = B + ((size_t)(bcol0 + rL))*K + glog*8;
  const size_t KH = (size_t)128 * K;
  const int sdst = w*512;

  const int goff = (kg ^ ((fr >> 1) & 3)) * 8;
  const int aro = wm*4096 + fr*32 + goff;
  const int bro = 32768 + (wn>>1)*4096 + (wn&1)*2048 + fr*32 + goff;

  f32x4 acc[8][4] = {};
  bf16x8 bfr[4];

  auto STG_A = [&](int kt){
    int bo = (kt & 3)*8192;
    #pragma unroll
    for (int h = 0; h < 2; ++h)
      __builtin_amdgcn_global_load_lds((gaddr_t)(Asrc + h*KH + kt*32),
          (laddr_t)(LDS + bo + h*4096 + sdst), 16, 0, 0);
  };
  auto STG_B = [&](int kt){
    int bo = 32768 + (kt & 3)*8192;
    #pragma unroll
    for (int h = 0; h < 2; ++h)
      __builtin_amdgcn_global_load_lds((gaddr_t)(Bsrc + h*KH + kt*32),
          (laddr_t)(LDS + bo + h*4096 + sdst), 16, 0, 0);
  };

  auto TILE = [&](int kt, int stg, int wait){
    const int ab = (kt & 3)*8192 + aro;
    const int bb = (kt & 3)*8192 + bro;
    bf16x8 af[4];
    #pragma unroll
    for (int m = 0; m < 4; ++m) af[m] = *(const bf16x8*)&LDS[ab + m*512];
    #pragma unroll
    for (int n = 0; n < 4; ++n) bfr[n] = *(const bf16x8*)&LDS[bb + n*512];
    if (stg) STG_A(kt + 3);
    __builtin_amdgcn_s_barrier();
    __builtin_amdgcn_s_setprio(1);
    #pragma unroll
    for (int m = 0; m < 4; ++m)
      #pragma unroll
      for (int n = 0; n < 4; ++n)
        acc[m][n] = MFMA_BF16(af[m], bfr[n], acc[m][n]);
    __builtin_amdgcn_s_setprio(0);
    __builtin_amdgcn_s_barrier();
    #pragma unroll
    for (int m = 0; m < 4; ++m) af[m] = *(const bf16x8*)&LDS[ab + (m+4)*512];
    if (stg) STG_B(kt + 3);
    __builtin_amdgcn_s_barrier();
    __builtin_amdgcn_s_setprio(1);
    #pragma unroll
    for (int m = 0; m < 4; ++m)
      #pragma unroll
      for (int n = 0; n < 4; ++n)
        acc[m+4][n] = MFMA_BF16(af[m], bfr[n], acc[m+4][n]);
    __builtin_amdgcn_s_setprio(0);
    if (wait == 2){ asm volatile("s_waitcnt vmcnt(8)" ::: "memory"); }
    else if (wait == 1){ asm volatile("s_waitcnt vmcnt(4)" ::: "memory"); }
    else if (wait == 0){ asm volatile("s_waitcnt vmcnt(0)" ::: "memory"); }
    __builtin_amdgcn_sched_barrier(0);
    __builtin_amdgcn_s_barrier();
  };

  STG_A(0); STG_B(0); STG_A(1); STG_B(1); STG_A(2); STG_B(2);
  asm volatile("s_waitcnt vmcnt(8)" ::: "memory");
  __builtin_amdgcn_sched_barrier(0);
  __builtin_amdgcn_s_barrier();

  #pragma unroll 1
  for (int kt = 0; kt < NT - 3; ++kt) TILE(kt, 1, 2);
  TILE(NT-3, 0, 1);
  TILE(NT-2, 0, 0);
  TILE(NT-1, 0, -1);

  const int rbase = wm*128 + (lane >> 4)*4;
  const int cbase = wn*64 + fr;
  #pragma unroll
  for (int M = 0; M < 8; ++M){
    #pragma unroll
    for (int Np = 0; Np < 4; ++Np){
      #pragma unroll
      for (int j = 0; j < 4; ++j){
        float v = acc[M][Np][j];
        size_t gr = arow0 + rbase + M*16 + j;
        int gc = bcol0 + cbase + Np*16;
        if constexpr (EPI == EPI_BF16){
          ((u16*)C)[gr*(size_t)N + gc] = f2b(v);
        } else if constexpr (EPI == EPI_OUTF32){
          ((float*)C)[gr*(size_t)N + gc] = v;
        } else if constexpr (EPI == EPI_ADDXC){
          float xc = b2f(((const u16*)aux0)[gr*512 + gc]);
          ((u16*)C)[gr*512 + gc] = f2b(v + xc);
        } else { // EPI_AX
          float pv = __shfl_xor(v, 1);
          int odd = lane & 1;
          float re = odd ? pv : v;
          float im = odd ? v : pv;
          float m2 = re*re + im*im;
          if (gc < 1024){
            int mh = gc >> 1;
            float sc = m2 > 0.f ? sqrtf(m2)/(1.f + m2) : 0.f;  // sigmoid(log m) = m/(1+m)
            if (!odd){
              unsigned pk = (unsigned)f2b(re*sc) | ((unsigned)f2b(im*sc) << 16);
              ((unsigned*)aux0)[gr*512 + mh] = pk;             // interleaved complex a
            }
          } else {
            int mh = (gc - 1024) >> 1;
            float sc = sqrtf(m2);                              // xc = x2 * sqrt(m)
            u16 ob = f2b(v * sc);
            if (!odd) ((u16*)aux1)[gr*512 + mh] = ob;          // xc_re
            int t = (int)(gr & 4095);
            if (t != 4095)                                     // x_roll[t+1] = xc[t]
              ((u16*)aux2)[(gr+1)*1024 + (odd ? 512 + mh : mh)] = ob;
          }
        }
      }
    }
  }
}

// ---------------- scan: s_t = a_t*(s_{t-1}+u_t), chunked 3-phase ----------------
__global__ void scan_p1(const unsigned* __restrict__ aint, const unsigned* __restrict__ uint_,
                        float4* __restrict__ agg){
  int idx = blockIdx.x*256 + threadIdx.x;   // 4*64*512 = 131072
  int m = idx & 511, chunk = (idx >> 9) & 63, b = idx >> 15;
  size_t row = (size_t)b*4096 + chunk*64;
  float px=1.f, py=0.f, sx=0.f, sy=0.f;
  for (int i = 0; i < 64; ++i, ++row){
    unsigned av = aint[row*512 + m];
    unsigned uv = uint_[row*512 + m];
    float ar = b2f((u16)av), ai = b2f((u16)(av>>16));
    float ur = b2f((u16)uv), ui = b2f((u16)(uv>>16));
    float tx2 = sx + ur, ty2 = sy + ui;
    sx = ar*tx2 - ai*ty2; sy = ar*ty2 + ai*tx2;
    float np = px*ar - py*ai; py = px*ai + py*ar; px = np;
  }
  agg[((size_t)(b*512+m))*64 + chunk] = make_float4(px,py,sx,sy);
}
__global__ void scan_p2(const float4* __restrict__ agg, float2* __restrict__ carry){
  int seq = blockIdx.x*256 + threadIdx.x;   // 2048
  float sx = 0.f, sy = 0.f;
  for (int c = 0; c < 64; ++c){
    carry[(size_t)seq*64 + c] = make_float2(sx, sy);
    float4 g = agg[(size_t)seq*64 + c];
    float nx = g.x*sx - g.y*sy + g.z;
    sy = g.x*sy + g.y*sx + g.w; sx = nx;
  }
}
__global__ void scan_p3(const unsigned* __restrict__ aint, const unsigned* __restrict__ uint_,
                        const float2* __restrict__ carry, unsigned* __restrict__ sout){
  int idx = blockIdx.x*256 + threadIdx.x;
  int m = idx & 511, chunk = (idx >> 9) & 63, b = idx >> 15;
  size_t row = (size_t)b*4096 + chunk*64;
  float2 c0 = carry[((size_t)(b*512+m))*64 + chunk];
  float sx = c0.x, sy = c0.y;
  for (int i = 0; i < 64; ++i, ++row){
    unsigned av = aint[row*512 + m];
    unsigned uv = uint_[row*512 + m];
    float ar = b2f((u16)av), ai = b2f((u16)(av>>16));
    float ur = b2f((u16)uv), ui = b2f((u16)(uv>>16));
    float tx2 = sx + ur, ty2 = sy + ui;
    sx = ar*tx2 - ai*ty2; sy = ar*ty2 + ai*tx2;
    sout[row*512 + m] = (unsigned)f2b(sx) | ((unsigned)f2b(sy) << 16);
  }
}

// ---------------- host ----------------
extern "C" void kernel_launch(void* const* d_in, const int* in_sizes, int n_in,
                              void* d_out, int out_size, void* d_ws, size_t ws_size,
                              hipStream_t stream){
  (void)in_sizes; (void)n_in; (void)out_size; (void)ws_size;
  const float* x   = (const float*)d_in[0];
  const float* wa  = (const float*)d_in[1];
  const float* wx  = (const float*)d_in[2];
  const float* wo  = (const float*)d_in[3];
  const float* vr  = (const float*)d_in[4];
  const float* vi  = (const float*)d_in[5];
  const float* lhr = (const float*)d_in[6];
  const float* lhi = (const float*)d_in[7];

  char* ws = (char*)d_ws;
  const size_t SB = 16384ull*1024*2;      // 33.5 MB
  const size_t HB = SB/2;
  u16* Xb    = (u16*)(ws);                // later reused as U
  unsigned* AINT = (unsigned*)(ws + SB);  // interleaved a ; later HRE
  u16* XROLL = (u16*)(ws + 2*SB);         // later reused as S
  u16* XCRE  = (u16*)(ws + 3*SB);
  char* p = ws + 3*SB + HB;
  u16* WABb  = (u16*)p; p += 4194304;     // [WA;WX] 2048x1024 bf16
  u16* MINV  = (u16*)p; p += 2097152;
  u16* MV4   = (u16*)p; p += 1048576;
  u16* WOUTb = (u16*)p; p += 1048576;
  float2* PBUFg = (float2*)p; p += 16ull*16384*8;   // 2 MB
  float2* BINVg = (float2*)p; p += 16ull*1024*8;    // 128 KB
  int*    FLAG  = (int*)p;   p += 256;
  float4* AGG   = (float4*)p; p += 2048ull*64*16;
  float2* CARRY = (float2*)p; p += 2048ull*64*8;
  u16* U   = Xb;
  u16* S   = XROLL;
  u16* HRE = (u16*)AINT;

  hipMemsetAsync(FLAG, 0, 256, stream);

  cast_all<<<2048,256,0,stream>>>(x, wa, wx, wo, vr, vi, lhr, lhi,
                                  Xb, WABb, WOUTb, MV4, XROLL);

  const size_t ILDS = 131072 + 16896 + 8448;   // 156416
  inv_pipe<<<32,1024,ILDS,stream>>>(vr, vi, PBUFg, BINVg, FLAG, MINV);

  const size_t GLDS = 131072;
  gemm256<EPI_AX><<<512,512,GLDS,stream>>>(Xb, WABb, 1024, 32, 2048, 3,
                                           nullptr, (void*)AINT, (void*)XCRE, (void*)XROLL);
  gemm256<EPI_BF16><<<256,512,GLDS,stream>>>(XROLL, MINV, 1024, 32, 1024, 2,
                                             (void*)U, nullptr, nullptr, nullptr);

  scan_p1<<<512,256,0,stream>>>((const unsigned*)AINT, (const unsigned*)U, AGG);
  scan_p2<<<8,256,0,stream>>>(AGG, CARRY);
  scan_p3<<<512,256,0,stream>>>((const unsigned*)AINT, (const unsigned*)U, CARRY, (unsigned*)S);

  gemm256<EPI_ADDXC><<<128,512,GLDS,stream>>>(S, MV4, 1024, 32, 512, 1,
                                              (void*)HRE, (void*)XCRE, nullptr, nullptr);
  gemm256<EPI_OUTF32><<<256,512,GLDS,stream>>>(HRE, WOUTb, 512, 16, 1024, 2,
                                               d_out, nullptr, nullptr, nullptr);
}